// Round 4
// baseline (503.103 us; speedup 1.0000x reference)
//
#include <hip/hip_runtime.h>
#include <hip/hip_bf16.h>
#include <cstdint>
#include <cstddef>

#define IN_DIM 512
#define HID 256
#define OUTD 64
#define NEG_SLOPE 0.2f

typedef __attribute__((ext_vector_type(8))) __bf16 bfrag_t;      // MFMA A/B operand
typedef __attribute__((ext_vector_type(4))) float facc_t;        // MFMA C/D
typedef __attribute__((ext_vector_type(4))) unsigned int u32x4;  // 16B copies

__device__ __forceinline__ float bf2f(unsigned short u) {
  return __uint_as_float(((unsigned int)u) << 16);
}
__device__ __forceinline__ unsigned short f2bf(float f) {
  unsigned int x = __float_as_uint(f);
  x = (x + 0x7FFFu + ((x >> 16) & 1u)) >> 16;  // RNE
  return (unsigned short)x;
}

// async global->LDS 16B/lane; LDS dst is wave-uniform base + lane*16 [m97/m104]
#define GLOAD_LDS16(g, l)                                              \
  __builtin_amdgcn_global_load_lds(                                    \
      (const __attribute__((address_space(1))) void*)(g),              \
      (__attribute__((address_space(3))) void*)(l), 16, 0, 0)

// ---------------- MFMA GEMM, B^T layout: C[m,n] = sum_k A[m,k] * B[n,k] ----------------
// A: [M,K] bf16. B: [N,K] bf16. C: fp32 if c32 else bf16; optional extra bf16 copy Cb.
// act!=0 applies elu to the fp32 acc before store.
// K % 32 == 0, N % BN == 0. Block = 256 = 4 waves (2x2 wave grid).
template <int BM, int BN>
__global__ __launch_bounds__(256) void gemm_bt(const unsigned short* __restrict__ A,
                                               const unsigned short* __restrict__ B,
                                               void* __restrict__ Craw,
                                               unsigned short* __restrict__ Cb,
                                               int M, int N, int K, int c32, int act) {
  constexpr int FM = BM / 32, FN = BN / 32;
  constexpr int RT = BM + BN;
  __shared__ __align__(16) unsigned short lds[RT * 32];

  const int bm0 = blockIdx.x * BM;
  const int bn0 = blockIdx.y * BN;
  const int tid = threadIdx.x;
  const int lane = tid & 63;
  const int wave = tid >> 6;
  const int wrow = (wave >> 1) * (BM / 2);
  const int wcol = (wave & 1) * (BN / 2);
  const int lr = lane & 15;
  const int quad = lane >> 4;
  const int swz = (quad ^ (lr & 3)) << 3;  // swizzled 8-elem slot within 32-elem row

  facc_t acc[FM][FN];
#pragma unroll
  for (int i = 0; i < FM; ++i)
#pragma unroll
    for (int j = 0; j < FN; ++j) acc[i][j] = (facc_t){0.f, 0.f, 0.f, 0.f};

  for (int k0 = 0; k0 < K; k0 += 32) {
    __syncthreads();  // previous iter's ds_reads done before overwrite
#pragma unroll
    for (int t = wave; t < RT / 16; t += 4) {
      const int r0 = t * 16;  // uniform per instr; A/B split is 16-row aligned
      const int row = r0 + (lane >> 2);
      const int seg = (lane & 3) ^ (row & 3);
      const unsigned short* g;
      if (r0 < BM) {
        int gm = bm0 + row;
        if (gm >= M) gm = M - 1;  // clamp; stores guarded in epilogue
        g = A + (size_t)gm * K + k0 + seg * 8;
      } else {
        g = B + (size_t)(bn0 + row - BM) * K + k0 + seg * 8;
      }
      GLOAD_LDS16(g, lds + t * 512);
    }
    __syncthreads();  // compiler drains vmcnt(0) before barrier

    bfrag_t a[FM], b[FN];
#pragma unroll
    for (int i = 0; i < FM; ++i)
      a[i] = *(const bfrag_t*)&lds[(wrow + i * 16 + lr) * 32 + swz];
#pragma unroll
    for (int j = 0; j < FN; ++j)
      b[j] = *(const bfrag_t*)&lds[(BM + wcol + j * 16 + lr) * 32 + swz];
#pragma unroll
    for (int i = 0; i < FM; ++i)
#pragma unroll
      for (int j = 0; j < FN; ++j)
        acc[i][j] = __builtin_amdgcn_mfma_f32_16x16x32_bf16(a[i], b[j], acc[i][j], 0, 0, 0);
  }

  // C/D layout: col=lane&15, row=quad*4+reg  [verified m89/m91]
#pragma unroll
  for (int i = 0; i < FM; ++i)
#pragma unroll
    for (int r = 0; r < 4; ++r) {
      const int grow = bm0 + wrow + i * 16 + quad * 4 + r;
      if (grow < M) {
#pragma unroll
        for (int j = 0; j < FN; ++j) {
          const int gcol = bn0 + wcol + j * 16 + lr;
          float v = acc[i][j][r];
          if (act) v = v > 0.f ? v : (expf(v) - 1.f);
          if (c32) ((float*)Craw)[(size_t)grow * N + gcol] = v;
          else ((unsigned short*)Craw)[(size_t)grow * N + gcol] = f2bf(v);
          if (Cb) Cb[(size_t)grow * N + gcol] = f2bf(v);
        }
      }
    }
}

// ---- conv1 variant: A fp32 (converted during reg-staging), BN == N (one col-block),
// rowdot (att_src/att_dst dots) fused into the epilogue -> as_/ad_ written here.
// Deletes the separate rowdot kernel's 25.6 MB hp1 re-read.
template <int BM, int BN>
__global__ __launch_bounds__(256) void gemm_a32_bt_att(const float* __restrict__ A,
                                                       const unsigned short* __restrict__ B,
                                                       unsigned short* __restrict__ C,
                                                       const float* __restrict__ att_s,
                                                       const float* __restrict__ att_d,
                                                       float* __restrict__ as_,
                                                       float* __restrict__ ad_,
                                                       int M, int N, int K) {
  constexpr int FM = BM / 32, FN = BN / 32;
  constexpr int RT = BM + BN;
  __shared__ __align__(16) unsigned short lds[RT * 32];

  const int bm0 = blockIdx.x * BM;
  const int tid = threadIdx.x;
  const int lane = tid & 63;
  const int wave = tid >> 6;
  const int wrow = (wave >> 1) * (BM / 2);
  const int wcol = (wave & 1) * (BN / 2);
  const int lr = lane & 15;
  const int quad = lane >> 4;
  const int swz = (quad ^ (lr & 3)) << 3;

  const int arow0 = tid >> 2;  // A staging: rows 0..63 (x2 halves)
  const int aseg = tid & 3;

  facc_t acc[FM][FN];
#pragma unroll
  for (int i = 0; i < FM; ++i)
#pragma unroll
    for (int j = 0; j < FN; ++j) acc[i][j] = (facc_t){0.f, 0.f, 0.f, 0.f};

  for (int k0 = 0; k0 < K; k0 += 32) {
    __syncthreads();
    // B rows -> lds rows [BM, BM+BN) via async DMA (pre-swizzled source)
#pragma unroll
    for (int t = wave; t < BN / 16; t += 4) {
      const int lr0 = BM + t * 16;
      const int row = lr0 + (lane >> 2);
      const int seg = (lane & 3) ^ (row & 3);
      const unsigned short* g = B + (size_t)(t * 16 + (lane >> 2)) * K + k0 + seg * 8;
      GLOAD_LDS16(g, lds + lr0 * 32);
    }
    // A rows via regs: load 8 fp32, cvt bf16x8, ds_write_b128 to swizzled slot
#pragma unroll
    for (int h = 0; h < 2; ++h) {
      const int row = arow0 + h * (BM / 2);
      int gm = bm0 + row;
      if (gm >= M) gm = M - 1;
      const float* g = A + (size_t)gm * K + k0 + aseg * 8;
      const float4 fa = ((const float4*)g)[0];
      const float4 fb = ((const float4*)g)[1];
      u32x4 pk;
      pk.x = (unsigned int)f2bf(fa.x) | ((unsigned int)f2bf(fa.y) << 16);
      pk.y = (unsigned int)f2bf(fa.z) | ((unsigned int)f2bf(fa.w) << 16);
      pk.z = (unsigned int)f2bf(fb.x) | ((unsigned int)f2bf(fb.y) << 16);
      pk.w = (unsigned int)f2bf(fb.z) | ((unsigned int)f2bf(fb.w) << 16);
      *(u32x4*)&lds[row * 32 + ((aseg ^ (row & 3)) << 3)] = pk;
    }
    __syncthreads();

    bfrag_t a[FM], b[FN];
#pragma unroll
    for (int i = 0; i < FM; ++i)
      a[i] = *(const bfrag_t*)&lds[(wrow + i * 16 + lr) * 32 + swz];
#pragma unroll
    for (int j = 0; j < FN; ++j)
      b[j] = *(const bfrag_t*)&lds[(BM + wcol + j * 16 + lr) * 32 + swz];
#pragma unroll
    for (int i = 0; i < FM; ++i)
#pragma unroll
      for (int j = 0; j < FN; ++j)
        acc[i][j] = __builtin_amdgcn_mfma_f32_16x16x32_bf16(a[i], b[j], acc[i][j], 0, 0, 0);
  }

  // att vectors for this lane's columns
  float av_s[FN], av_d[FN];
#pragma unroll
  for (int j = 0; j < FN; ++j) {
    av_s[j] = att_s[wcol + j * 16 + lr];
    av_d[j] = att_d[wcol + j * 16 + lr];
  }
  float* redS = (float*)lds;         // [2][BM]
  float* redD = (float*)lds + 2 * BM;
  __syncthreads();  // all waves done with tile LDS before reuse

#pragma unroll
  for (int i = 0; i < FM; ++i)
#pragma unroll
    for (int r = 0; r < 4; ++r) {
      const int grow = bm0 + wrow + i * 16 + quad * 4 + r;
      float ps = 0.f, pd = 0.f;
#pragma unroll
      for (int j = 0; j < FN; ++j) {
        const float v = acc[i][j][r];
        ps += v * av_s[j];
        pd += v * av_d[j];
        if (grow < M) C[(size_t)grow * N + (wcol + j * 16 + lr)] = f2bf(v);
      }
      ps += __shfl_xor(ps, 1); ps += __shfl_xor(ps, 2);
      ps += __shfl_xor(ps, 4); ps += __shfl_xor(ps, 8);
      pd += __shfl_xor(pd, 1); pd += __shfl_xor(pd, 2);
      pd += __shfl_xor(pd, 4); pd += __shfl_xor(pd, 8);
      if (lr == 0) {
        const int rloc = wrow + i * 16 + quad * 4 + r;
        redS[(wave & 1) * BM + rloc] = ps;
        redD[(wave & 1) * BM + rloc] = pd;
      }
    }
  __syncthreads();
  if (tid < BM) {
    const int grow = bm0 + tid;
    if (grow < M) {
      as_[grow] = redS[tid] + redS[BM + tid];
      ad_[grow] = redD[tid] + redD[BM + tid];
    }
  }
}

// ---------------- conversions ----------------
// all four weight conversions in one launch (W1: 512x256, W2: 256x64)
__global__ void cvt_weights(const float* __restrict__ W1, const float* __restrict__ W2,
                            unsigned short* __restrict__ W1T, unsigned short* __restrict__ W1b,
                            unsigned short* __restrict__ W2T, unsigned short* __restrict__ W2b) {
  const int idx = blockIdx.x * 256 + threadIdx.x;
  if (idx < IN_DIM * HID) {
    const unsigned short b = f2bf(W1[idx]);
    W1b[idx] = b;
    const int r = idx >> 8, c = idx & 255;  // W1 row-major [512,256]
    W1T[(size_t)c * IN_DIM + r] = b;
  }
  if (idx < HID * OUTD) {
    const unsigned short b = f2bf(W2[idx]);
    W2b[idx] = b;
    const int r = idx >> 6, c = idx & 63;  // W2 row-major [256,64]
    W2T[(size_t)c * HID + r] = b;
  }
}

__global__ void init_deg(int* __restrict__ deg, int n) {
  const int i = blockIdx.x * 256 + threadIdx.x;
  if (i < n) deg[i] = 0;
}

// per-edge exp(leaky_relu(logit)) + degree count. NO denom atomics: normalization is
// done inside the prop kernels (sum ex alongside sum ex*h, divide once).
__global__ void edge_pass1(const int* __restrict__ src, const int* __restrict__ dst,
                           const float* __restrict__ as_, const float* __restrict__ ad_,
                           float* __restrict__ eexp, int* __restrict__ deg, int E, int n) {
  const int e = blockIdx.x * 256 + threadIdx.x;
  if (e >= E) return;
  const int s = src[e], d = dst[e];
  if ((unsigned)s >= (unsigned)n || (unsigned)d >= (unsigned)n) return;
  float l = as_[s] + ad_[d];
  l = l > 0.f ? l : NEG_SLOPE * l;
  eexp[e] = expf(fminf(l, 60.f));
  atomicAdd(&deg[d], 1);
}

// ---------------- hierarchical scan ----------------
__global__ __launch_bounds__(256) void scan_reduce(const int* __restrict__ deg,
                                                   int* __restrict__ bsum, int n) {
  __shared__ int ws4[4];
  const int tid = threadIdx.x, lane = tid & 63, wid = tid >> 6;
  const int base = blockIdx.x * 2048 + tid * 8;
  int s = 0;
#pragma unroll
  for (int j = 0; j < 8; ++j) {
    const int i = base + j;
    if (i < n) s += deg[i];
  }
  for (int off = 32; off > 0; off >>= 1) s += __shfl_down(s, off);
  if (lane == 0) ws4[wid] = s;
  __syncthreads();
  if (tid == 0) bsum[blockIdx.x] = ws4[0] + ws4[1] + ws4[2] + ws4[3];
}

__global__ __launch_bounds__(256) void scan_final(const int* __restrict__ deg,
                                                  const int* __restrict__ bsum,
                                                  int* __restrict__ row_ptr,
                                                  int* __restrict__ cursor, int n) {
  __shared__ int wsum[4];
  __shared__ int blockoff;
  const int tid = threadIdx.x, lane = tid & 63, wid = tid >> 6;
  if (wid == 0) {
    int v = (lane < blockIdx.x) ? bsum[lane] : 0;
    for (int off = 32; off > 0; off >>= 1) v += __shfl_down(v, off);
    if (lane == 0) blockoff = v;
  }
  const int base = blockIdx.x * 2048 + tid * 8;
  int v[8], s = 0;
#pragma unroll
  for (int j = 0; j < 8; ++j) {
    const int i = base + j;
    v[j] = (i < n) ? deg[i] : 0;
    s += v[j];
  }
  int ws = s;
  for (int off = 1; off < 64; off <<= 1) {
    const int t = __shfl_up(ws, off);
    if (lane >= off) ws += t;
  }
  if (lane == 63) wsum[wid] = ws;
  __syncthreads();
  int woff = 0;
  for (int w_ = 0; w_ < wid; ++w_) woff += wsum[w_];
  int run = blockoff + woff + (ws - s);
#pragma unroll
  for (int j = 0; j < 8; ++j) {
    const int i = base + j;
    if (i < n) {
      cursor[i] = run;
      row_ptr[i + 1] = run + v[j];
    }
    run += v[j];
  }
  if (blockIdx.x == 0 && tid == 0) row_ptr[0] = 0;
}

// CSR entry interleaved: .x = src node, .y = exp-weight bits (one 8B txn per edge)
__global__ void edge_scatter(const int* __restrict__ src, const int* __restrict__ dst,
                             const float* __restrict__ eexp, int* __restrict__ cursor,
                             int2* __restrict__ csr, int E, int n) {
  const int e = blockIdx.x * 256 + threadIdx.x;
  if (e >= E) return;
  const int s = src[e], d = dst[e];
  if ((unsigned)s >= (unsigned)n || (unsigned)d >= (unsigned)n) return;
  const int pos = atomicAdd(&cursor[d], 1);
  int2 c;
  c.x = s;
  c.y = __float_as_int(eexp[e]);
  csr[pos] = c;
}

// out[d,:] = elu( (sum_e ex_e * hpre[src_e,:]) / (sum ex + eps) ), 256-dim rows.
// Edge list preloaded into lane regs (1 coalesced 8B load/lane, deg<=64), shfl-
// distributed; predicated unified 16-edge/iter loop (no csr latency chain, no
// serialized tail). half-wave (32 lanes x 16B = 512B row) per edge slot.
__global__ __launch_bounds__(256) void gat_prop256(const unsigned short* __restrict__ hpre,
                                                   const int* __restrict__ row_ptr,
                                                   const int2* __restrict__ csr,
                                                   unsigned short* __restrict__ out, int n) {
  const int node = blockIdx.x * 4 + (threadIdx.x >> 6);
  if (node >= n) return;
  const int lane = threadIdx.x & 63;
  const int half = lane >> 5;
  const int lh = lane & 31;
  const int beg = row_ptr[node], end = row_ptr[node + 1];
  const int deg = end - beg;
  const unsigned short* base = hpre + (lh << 3);
  float a[8] = {0.f, 0.f, 0.f, 0.f, 0.f, 0.f, 0.f, 0.f};
  float wsum = 0.f;

  int cs = 0;
  float cw = 0.f;
  if (lane < deg) {
    const int2 t = csr[beg + lane];
    cs = t.x;
    cw = __int_as_float(t.y);
  }
  const int dmain = deg < 64 ? deg : 64;
  for (int j0 = 0; j0 < dmain; j0 += 16) {
#pragma unroll
    for (int u = 0; u < 8; ++u) {
      const int j = j0 + 2 * u + half;
      const bool valid = j < dmain;
      const int jj = valid ? j : 0;
      const int s = __shfl(cs, jj);
      float w = __shfl(cw, jj);
      w = valid ? w : 0.f;
      const u32x4 v = *(const u32x4*)(base + (size_t)s * HID);
      wsum += w;
      a[0] += w * bf2f((unsigned short)(v.x & 0xffffu));
      a[1] += w * bf2f((unsigned short)(v.x >> 16));
      a[2] += w * bf2f((unsigned short)(v.y & 0xffffu));
      a[3] += w * bf2f((unsigned short)(v.y >> 16));
      a[4] += w * bf2f((unsigned short)(v.z & 0xffffu));
      a[5] += w * bf2f((unsigned short)(v.z >> 16));
      a[6] += w * bf2f((unsigned short)(v.w & 0xffffu));
      a[7] += w * bf2f((unsigned short)(v.w >> 16));
    }
  }
  // rare tail: deg > 64
  for (int e = beg + 64; e < end; e += 2) {
    const int e2 = e + half;
    if (e2 < end) {
      const int2 c = csr[e2];
      const float w = __int_as_float(c.y);
      const u32x4 v = *(const u32x4*)(base + (size_t)c.x * HID);
      wsum += w;
      a[0] += w * bf2f((unsigned short)(v.x & 0xffffu));
      a[1] += w * bf2f((unsigned short)(v.x >> 16));
      a[2] += w * bf2f((unsigned short)(v.y & 0xffffu));
      a[3] += w * bf2f((unsigned short)(v.y >> 16));
      a[4] += w * bf2f((unsigned short)(v.z & 0xffffu));
      a[5] += w * bf2f((unsigned short)(v.z >> 16));
      a[6] += w * bf2f((unsigned short)(v.w & 0xffffu));
      a[7] += w * bf2f((unsigned short)(v.w >> 16));
    }
  }
#pragma unroll
  for (int i = 0; i < 8; ++i) a[i] += __shfl_xor(a[i], 32);
  wsum += __shfl_xor(wsum, 32);
  if (half == 0) {
    const float inv = 1.f / (wsum + 1e-16f);
#pragma unroll
    for (int i = 0; i < 8; ++i) {
      a[i] *= inv;
      a[i] = a[i] > 0.f ? a[i] : (expf(a[i]) - 1.f);
    }
    u32x4 o;
    o.x = (unsigned int)f2bf(a[0]) | ((unsigned int)f2bf(a[1]) << 16);
    o.y = (unsigned int)f2bf(a[2]) | ((unsigned int)f2bf(a[3]) << 16);
    o.z = (unsigned int)f2bf(a[4]) | ((unsigned int)f2bf(a[5]) << 16);
    o.w = (unsigned int)f2bf(a[6]) | ((unsigned int)f2bf(a[7]) << 16);
    *(u32x4*)(out + (size_t)node * HID + (lh << 3)) = o;
  }
}

// g2[d,:] = (sum_e ex_e * h2[src_e,:]) / (sum ex + eps), 64-dim rows, NO elu (fused
// into the following gemm via linearity). Same preload+predication; quarter-wave
// (16 lanes x 8B = 128B row) per edge slot; 16 edges/iter.
__global__ __launch_bounds__(256) void gat_prop64(const unsigned short* __restrict__ hpre,
                                                  const int* __restrict__ row_ptr,
                                                  const int2* __restrict__ csr,
                                                  unsigned short* __restrict__ out, int n) {
  const int node = blockIdx.x * 4 + (threadIdx.x >> 6);
  if (node >= n) return;
  const int lane = threadIdx.x & 63;
  const int quad = lane >> 4;
  const int lr = lane & 15;
  const int beg = row_ptr[node], end = row_ptr[node + 1];
  const int deg = end - beg;
  const unsigned short* base = hpre + (lr << 2);
  float a0 = 0.f, a1 = 0.f, a2 = 0.f, a3 = 0.f, wsum = 0.f;

  int cs = 0;
  float cw = 0.f;
  if (lane < deg) {
    const int2 t = csr[beg + lane];
    cs = t.x;
    cw = __int_as_float(t.y);
  }
  const int dmain = deg < 64 ? deg : 64;
  for (int j0 = 0; j0 < dmain; j0 += 16) {
#pragma unroll
    for (int u = 0; u < 4; ++u) {
      const int j = j0 + 4 * u + quad;
      const bool valid = j < dmain;
      const int jj = valid ? j : 0;
      const int s = __shfl(cs, jj);
      float w = __shfl(cw, jj);
      w = valid ? w : 0.f;
      const uint2 v = *(const uint2*)(base + (size_t)s * OUTD);
      wsum += w;
      a0 += w * bf2f((unsigned short)(v.x & 0xffffu));
      a1 += w * bf2f((unsigned short)(v.x >> 16));
      a2 += w * bf2f((unsigned short)(v.y & 0xffffu));
      a3 += w * bf2f((unsigned short)(v.y >> 16));
    }
  }
  for (int e = beg + 64; e < end; e += 4) {
    const int e2 = e + quad;
    if (e2 < end) {
      const int2 c = csr[e2];
      const float w = __int_as_float(c.y);
      const uint2 v = *(const uint2*)(base + (size_t)c.x * OUTD);
      wsum += w;
      a0 += w * bf2f((unsigned short)(v.x & 0xffffu));
      a1 += w * bf2f((unsigned short)(v.x >> 16));
      a2 += w * bf2f((unsigned short)(v.y & 0xffffu));
      a3 += w * bf2f((unsigned short)(v.y >> 16));
    }
  }
  a0 += __shfl_xor(a0, 16); a0 += __shfl_xor(a0, 32);
  a1 += __shfl_xor(a1, 16); a1 += __shfl_xor(a1, 32);
  a2 += __shfl_xor(a2, 16); a2 += __shfl_xor(a2, 32);
  a3 += __shfl_xor(a3, 16); a3 += __shfl_xor(a3, 32);
  wsum += __shfl_xor(wsum, 16); wsum += __shfl_xor(wsum, 32);
  if (quad == 0) {
    const float inv = 1.f / (wsum + 1e-16f);
    uint2 o;
    o.x = (unsigned int)f2bf(a0 * inv) | ((unsigned int)f2bf(a1 * inv) << 16);
    o.y = (unsigned int)f2bf(a2 * inv) | ((unsigned int)f2bf(a3 * inv) << 16);
    *(uint2*)(out + (size_t)node * OUTD + (lr << 2)) = o;
  }
}

extern "C" void kernel_launch(void* const* d_in, const int* in_sizes, int n_in,
                              void* d_out, int out_size, void* d_ws, size_t ws_size,
                              hipStream_t stream) {
  const float* feat = (const float*)d_in[0];   // [N, 512] fp32
  const float* W1 = (const float*)d_in[1];     // [512, 256] fp32
  const float* W2 = (const float*)d_in[2];     // [256, 64] fp32
  const float* att_s = (const float*)d_in[3];  // [256] fp32
  const float* att_d = (const float*)d_in[4];  // [256] fp32
  const int* ei = (const int*)d_in[5];         // [2, E] int32
  const int N = in_sizes[0] / IN_DIM;          // 50000
  const int E = in_sizes[5] / 2;               // 600000
  const int* src = ei;
  const int* dst = ei + E;
  float* outf = (float*)d_out;  // h2 [N,64] fp32 ++ h4 [N,512] fp32

  // Park hp1/g2 in the not-yet-written h4 slot. Lifetimes strictly sequential:
  // hp1 dead after gat_prop256; g2 dead after the conv3' gemm; conv4 writes the
  // slot last reading only ws.
  unsigned short* hp1 = (unsigned short*)(outf + (size_t)N * OUTD);  // [N,256] bf16
  unsigned short* g2 = hp1 + (size_t)N * HID;                        // [N,64] bf16

  // ---- workspace carve-up (256B-aligned) ----
  char* w = (char*)d_ws;
  size_t off = 0;
  auto alloc = [&](size_t bytes) -> void* {
    void* p = w + off;
    off += (bytes + 255) & ~(size_t)255;
    return p;
  };
  unsigned short* h1h3 = (unsigned short*)alloc((size_t)N * HID * 2);  // h1, then h3
  unsigned short* h2b = (unsigned short*)alloc((size_t)N * OUTD * 2);  // h2 bf16
  float* a_src_v = (float*)alloc((size_t)N * 4);
  float* a_dst_v = (float*)alloc((size_t)N * 4);
  float* eexp = (float*)alloc((size_t)E * 4);
  int* deg = (int*)alloc((size_t)N * 4);
  int* row_ptr = (int*)alloc((size_t)(N + 1) * 4);
  int* cursor = (int*)alloc((size_t)N * 4);
  int* bsum = (int*)alloc((size_t)64 * 4);
  int2* csr = (int2*)alloc((size_t)E * 8);
  unsigned short* W1T = (unsigned short*)alloc((size_t)IN_DIM * HID * 2);  // [256,512] bf16
  unsigned short* W1b = (unsigned short*)alloc((size_t)IN_DIM * HID * 2);  // [512,256] bf16
  unsigned short* W2T = (unsigned short*)alloc((size_t)HID * OUTD * 2);    // [64,256] bf16
  unsigned short* W2b = (unsigned short*)alloc((size_t)HID * OUTD * 2);    // [256,64] bf16

  const int EB = (E + 255) / 256;
  const int NB = (N + 255) / 256;
  const int MB = (N + 127) / 128;
  const int SB = (N + 2047) / 2048;  // scan blocks (25 for N=50000; must be <= 64)

  // weight conversions (one launch)
  cvt_weights<<<(IN_DIM * HID + 255) / 256, 256, 0, stream>>>(W1, W2, W1T, W1b, W2T, W2b);

  // conv1: hp1 = feat @ W1 (fp32 A converted in staging) + fused rowdot -> as_/ad_
  gemm_a32_bt_att<128, 256><<<MB, 256, 0, stream>>>(feat, W1T, hp1, att_s, att_d,
                                                    a_src_v, a_dst_v, N, HID, IN_DIM);

  // edge softmax (tied: shared by conv1 & conv3) + dst-CSR build (no denom atomics)
  init_deg<<<NB, 256, 0, stream>>>(deg, N);
  edge_pass1<<<EB, 256, 0, stream>>>(src, dst, a_src_v, a_dst_v, eexp, deg, E, N);
  scan_reduce<<<SB, 256, 0, stream>>>(deg, bsum, N);
  scan_final<<<SB, 256, 0, stream>>>(deg, bsum, row_ptr, cursor, N);
  edge_scatter<<<EB, 256, 0, stream>>>(src, dst, eexp, cursor, csr, E, N);

  // conv1 propagate (self-normalizing) + elu -> h1 (bf16)
  gat_prop256<<<(N + 3) / 4, 256, 0, stream>>>(hp1, row_ptr, csr, h1h3, N);
  // conv2: h2 = h1 @ W2 -> outf (fp32) + h2b (bf16)
  gemm_bt<128, 64><<<dim3(MB, OUTD / 64), 256, 0, stream>>>(h1h3, W2T, outf, h2b,
                                                            N, OUTD, HID, 1, 0);
  // conv3 via linearity: g2 = prop(h2) [N,64], then h3 = elu(g2 @ W2^T)
  gat_prop64<<<(N + 3) / 4, 256, 0, stream>>>(h2b, row_ptr, csr, g2, N);
  gemm_bt<128, 256><<<dim3(MB, HID / 256), 256, 0, stream>>>(g2, W2b, h1h3, nullptr,
                                                             N, HID, OUTD, 0, 1);
  // conv4: h4 = h3 @ W1^T -> outf[N*64:] (fp32)
  gemm_bt<128, 256><<<dim3(MB, IN_DIM / 256), 256, 0, stream>>>(h1h3, W1b,
                                                                outf + (size_t)N * OUTD,
                                                                nullptr, N, IN_DIM, HID, 1, 0);
}

// Round 5
// 448.234 us; speedup vs baseline: 1.1224x; 1.1224x over previous
//
#include <hip/hip_runtime.h>
#include <hip/hip_bf16.h>
#include <cstdint>
#include <cstddef>

#define IN_DIM 512
#define HID 256
#define OUTD 64
#define NEG_SLOPE 0.2f

typedef __attribute__((ext_vector_type(8))) __bf16 bfrag_t;      // MFMA A/B operand
typedef __attribute__((ext_vector_type(4))) float facc_t;        // MFMA C/D
typedef __attribute__((ext_vector_type(4))) unsigned int u32x4;  // 16B copies

__device__ __forceinline__ float bf2f(unsigned short u) {
  return __uint_as_float(((unsigned int)u) << 16);
}
__device__ __forceinline__ unsigned short f2bf(float f) {
  unsigned int x = __float_as_uint(f);
  x = (x + 0x7FFFu + ((x >> 16) & 1u)) >> 16;  // RNE
  return (unsigned short)x;
}

// async global->LDS 16B/lane; LDS dst is wave-uniform base + lane*16 [m97/m104]
#define GLOAD_LDS16(g, l)                                              \
  __builtin_amdgcn_global_load_lds(                                    \
      (const __attribute__((address_space(1))) void*)(g),              \
      (__attribute__((address_space(3))) void*)(l), 16, 0, 0)

// ---------------- MFMA GEMM, B^T layout: C[m,n] = sum_k A[m,k] * B[n,k] ----------------
// A: [M,K] bf16. B: [N,K] bf16. C: fp32 if c32 else bf16; optional extra bf16 copy Cb.
// act!=0 applies elu to the fp32 acc before store.
// K % 32 == 0, N % BN == 0. Block = 256 = 4 waves (2x2 wave grid).
// BN kept at 128: BN=256 (acc[4][8]=128 VGPR) measured 96us w/ 5% MfmaUtil (R4) —
// register-pressure collapse. 128^2 config is the measured-good point.
template <int BM, int BN>
__global__ __launch_bounds__(256) void gemm_bt(const unsigned short* __restrict__ A,
                                               const unsigned short* __restrict__ B,
                                               void* __restrict__ Craw,
                                               unsigned short* __restrict__ Cb,
                                               int M, int N, int K, int c32, int act) {
  constexpr int FM = BM / 32, FN = BN / 32;
  constexpr int RT = BM + BN;
  __shared__ __align__(16) unsigned short lds[RT * 32];

  const int bm0 = blockIdx.x * BM;
  const int bn0 = blockIdx.y * BN;
  const int tid = threadIdx.x;
  const int lane = tid & 63;
  const int wave = tid >> 6;
  const int wrow = (wave >> 1) * (BM / 2);
  const int wcol = (wave & 1) * (BN / 2);
  const int lr = lane & 15;
  const int quad = lane >> 4;
  const int swz = (quad ^ (lr & 3)) << 3;  // swizzled 8-elem slot within 32-elem row

  facc_t acc[FM][FN];
#pragma unroll
  for (int i = 0; i < FM; ++i)
#pragma unroll
    for (int j = 0; j < FN; ++j) acc[i][j] = (facc_t){0.f, 0.f, 0.f, 0.f};

  for (int k0 = 0; k0 < K; k0 += 32) {
    __syncthreads();  // previous iter's ds_reads done before overwrite
#pragma unroll
    for (int t = wave; t < RT / 16; t += 4) {
      const int r0 = t * 16;  // uniform per instr; A/B split is 16-row aligned
      const int row = r0 + (lane >> 2);
      const int seg = (lane & 3) ^ (row & 3);
      const unsigned short* g;
      if (r0 < BM) {
        int gm = bm0 + row;
        if (gm >= M) gm = M - 1;  // clamp; stores guarded in epilogue
        g = A + (size_t)gm * K + k0 + seg * 8;
      } else {
        g = B + (size_t)(bn0 + row - BM) * K + k0 + seg * 8;
      }
      GLOAD_LDS16(g, lds + t * 512);
    }
    __syncthreads();  // compiler drains vmcnt(0) before barrier

    bfrag_t a[FM], b[FN];
#pragma unroll
    for (int i = 0; i < FM; ++i)
      a[i] = *(const bfrag_t*)&lds[(wrow + i * 16 + lr) * 32 + swz];
#pragma unroll
    for (int j = 0; j < FN; ++j)
      b[j] = *(const bfrag_t*)&lds[(BM + wcol + j * 16 + lr) * 32 + swz];
#pragma unroll
    for (int i = 0; i < FM; ++i)
#pragma unroll
      for (int j = 0; j < FN; ++j)
        acc[i][j] = __builtin_amdgcn_mfma_f32_16x16x32_bf16(a[i], b[j], acc[i][j], 0, 0, 0);
  }

  // C/D layout: col=lane&15, row=quad*4+reg  [verified m89/m91]
#pragma unroll
  for (int i = 0; i < FM; ++i)
#pragma unroll
    for (int r = 0; r < 4; ++r) {
      const int grow = bm0 + wrow + i * 16 + quad * 4 + r;
      if (grow < M) {
#pragma unroll
        for (int j = 0; j < FN; ++j) {
          const int gcol = bn0 + wcol + j * 16 + lr;
          float v = acc[i][j][r];
          if (act) v = v > 0.f ? v : (expf(v) - 1.f);
          if (c32) ((float*)Craw)[(size_t)grow * N + gcol] = v;
          else ((unsigned short*)Craw)[(size_t)grow * N + gcol] = f2bf(v);
          if (Cb) Cb[(size_t)grow * N + gcol] = f2bf(v);
        }
      }
    }
}

// ---- conv1 variant: A is fp32 (row-major [M,K]); converts to bf16 during reg-staging.
// Fuses the fp32->bf16 feature conversion into conv1 (no featb pass). BN=128.
template <int BM, int BN>
__global__ __launch_bounds__(256) void gemm_a32_bt(const float* __restrict__ A,
                                                   const unsigned short* __restrict__ B,
                                                   unsigned short* __restrict__ C,
                                                   int M, int N, int K) {
  constexpr int FM = BM / 32, FN = BN / 32;
  constexpr int RT = BM + BN;
  __shared__ __align__(16) unsigned short lds[RT * 32];

  const int bm0 = blockIdx.x * BM;
  const int bn0 = blockIdx.y * BN;
  const int tid = threadIdx.x;
  const int lane = tid & 63;
  const int wave = tid >> 6;
  const int wrow = (wave >> 1) * (BM / 2);
  const int wcol = (wave & 1) * (BN / 2);
  const int lr = lane & 15;
  const int quad = lane >> 4;
  const int swz = (quad ^ (lr & 3)) << 3;

  const int arow0 = tid >> 2;  // A staging: rows 0..63 (x2 halves)
  const int aseg = tid & 3;

  facc_t acc[FM][FN];
#pragma unroll
  for (int i = 0; i < FM; ++i)
#pragma unroll
    for (int j = 0; j < FN; ++j) acc[i][j] = (facc_t){0.f, 0.f, 0.f, 0.f};

  for (int k0 = 0; k0 < K; k0 += 32) {
    __syncthreads();
    // B rows -> lds rows [BM, BM+BN) via async DMA (pre-swizzled source)
#pragma unroll
    for (int t = wave; t < BN / 16; t += 4) {
      const int lr0 = BM + t * 16;
      const int row = lr0 + (lane >> 2);
      const int seg = (lane & 3) ^ (row & 3);
      const unsigned short* g = B + (size_t)(bn0 + t * 16 + (lane >> 2)) * K + k0 + seg * 8;
      GLOAD_LDS16(g, lds + lr0 * 32);
    }
    // A rows via regs: load 8 fp32, cvt bf16x8, ds_write_b128 to swizzled slot
#pragma unroll
    for (int h = 0; h < 2; ++h) {
      const int row = arow0 + h * (BM / 2);
      int gm = bm0 + row;
      if (gm >= M) gm = M - 1;
      const float* g = A + (size_t)gm * K + k0 + aseg * 8;
      const float4 fa = ((const float4*)g)[0];
      const float4 fb = ((const float4*)g)[1];
      u32x4 pk;
      pk.x = (unsigned int)f2bf(fa.x) | ((unsigned int)f2bf(fa.y) << 16);
      pk.y = (unsigned int)f2bf(fa.z) | ((unsigned int)f2bf(fa.w) << 16);
      pk.z = (unsigned int)f2bf(fb.x) | ((unsigned int)f2bf(fb.y) << 16);
      pk.w = (unsigned int)f2bf(fb.z) | ((unsigned int)f2bf(fb.w) << 16);
      *(u32x4*)&lds[row * 32 + ((aseg ^ (row & 3)) << 3)] = pk;
    }
    __syncthreads();

    bfrag_t a[FM], b[FN];
#pragma unroll
    for (int i = 0; i < FM; ++i)
      a[i] = *(const bfrag_t*)&lds[(wrow + i * 16 + lr) * 32 + swz];
#pragma unroll
    for (int j = 0; j < FN; ++j)
      b[j] = *(const bfrag_t*)&lds[(BM + wcol + j * 16 + lr) * 32 + swz];
#pragma unroll
    for (int i = 0; i < FM; ++i)
#pragma unroll
      for (int j = 0; j < FN; ++j)
        acc[i][j] = __builtin_amdgcn_mfma_f32_16x16x32_bf16(a[i], b[j], acc[i][j], 0, 0, 0);
  }

#pragma unroll
  for (int i = 0; i < FM; ++i)
#pragma unroll
    for (int r = 0; r < 4; ++r) {
      const int grow = bm0 + wrow + i * 16 + quad * 4 + r;
      if (grow < M) {
#pragma unroll
        for (int j = 0; j < FN; ++j) {
          const int gcol = bn0 + wcol + j * 16 + lr;
          C[(size_t)grow * N + gcol] = f2bf(acc[i][j][r]);
        }
      }
    }
}

// ---------------- conversions ----------------
// all four weight conversions in one launch (W1: 512x256, W2: 256x64)
__global__ void cvt_weights(const float* __restrict__ W1, const float* __restrict__ W2,
                            unsigned short* __restrict__ W1T, unsigned short* __restrict__ W1b,
                            unsigned short* __restrict__ W2T, unsigned short* __restrict__ W2b) {
  const int idx = blockIdx.x * 256 + threadIdx.x;
  if (idx < IN_DIM * HID) {
    const unsigned short b = f2bf(W1[idx]);
    W1b[idx] = b;
    const int r = idx >> 8, c = idx & 255;  // W1 row-major [512,256]
    W1T[(size_t)c * IN_DIM + r] = b;
  }
  if (idx < HID * OUTD) {
    const unsigned short b = f2bf(W2[idx]);
    W2b[idx] = b;
    const int r = idx >> 6, c = idx & 63;  // W2 row-major [256,64]
    W2T[(size_t)c * HID + r] = b;
  }
}

// a_s[i] = hp1[i,:] . att_src ; a_d[i] = hp1[i,:] . att_dst   (one wave per node)
__global__ __launch_bounds__(256) void rowdot(const unsigned short* __restrict__ hp,
                                              const float* __restrict__ att_s,
                                              const float* __restrict__ att_d,
                                              float* __restrict__ as_, float* __restrict__ ad_,
                                              int n) {
  const int node = blockIdx.x * 4 + (threadIdx.x >> 6);
  if (node >= n) return;
  const int lane = threadIdx.x & 63;
  const unsigned short* row = hp + (size_t)node * HID + (lane << 2);
  float s = 0.f, d = 0.f;
#pragma unroll
  for (int j = 0; j < 4; ++j) {
    const float h = bf2f(row[j]);
    s += h * att_s[(lane << 2) + j];
    d += h * att_d[(lane << 2) + j];
  }
  for (int off = 32; off > 0; off >>= 1) {
    s += __shfl_down(s, off);
    d += __shfl_down(d, off);
  }
  if (lane == 0) { as_[node] = s; ad_[node] = d; }
}

__global__ void init_deg(int* __restrict__ deg, int n) {
  const int i = blockIdx.x * 256 + threadIdx.x;
  if (i < n) deg[i] = 0;
}

// per-edge exp(leaky_relu(logit)) + degree count. NO denom atomics: normalization is
// done inside the prop kernels (sum ex alongside sum ex*h, divide once).
__global__ void edge_pass1(const int* __restrict__ src, const int* __restrict__ dst,
                           const float* __restrict__ as_, const float* __restrict__ ad_,
                           float* __restrict__ eexp, int* __restrict__ deg, int E, int n) {
  const int e = blockIdx.x * 256 + threadIdx.x;
  if (e >= E) return;
  const int s = src[e], d = dst[e];
  if ((unsigned)s >= (unsigned)n || (unsigned)d >= (unsigned)n) return;
  float l = as_[s] + ad_[d];
  l = l > 0.f ? l : NEG_SLOPE * l;
  eexp[e] = expf(fminf(l, 60.f));
  atomicAdd(&deg[d], 1);
}

// ---------------- hierarchical scan ----------------
__global__ __launch_bounds__(256) void scan_reduce(const int* __restrict__ deg,
                                                   int* __restrict__ bsum, int n) {
  __shared__ int ws4[4];
  const int tid = threadIdx.x, lane = tid & 63, wid = tid >> 6;
  const int base = blockIdx.x * 2048 + tid * 8;
  int s = 0;
#pragma unroll
  for (int j = 0; j < 8; ++j) {
    const int i = base + j;
    if (i < n) s += deg[i];
  }
  for (int off = 32; off > 0; off >>= 1) s += __shfl_down(s, off);
  if (lane == 0) ws4[wid] = s;
  __syncthreads();
  if (tid == 0) bsum[blockIdx.x] = ws4[0] + ws4[1] + ws4[2] + ws4[3];
}

__global__ __launch_bounds__(256) void scan_final(const int* __restrict__ deg,
                                                  const int* __restrict__ bsum,
                                                  int* __restrict__ row_ptr,
                                                  int* __restrict__ cursor, int n) {
  __shared__ int wsum[4];
  __shared__ int blockoff;
  const int tid = threadIdx.x, lane = tid & 63, wid = tid >> 6;
  if (wid == 0) {
    int v = (lane < blockIdx.x) ? bsum[lane] : 0;
    for (int off = 32; off > 0; off >>= 1) v += __shfl_down(v, off);
    if (lane == 0) blockoff = v;
  }
  const int base = blockIdx.x * 2048 + tid * 8;
  int v[8], s = 0;
#pragma unroll
  for (int j = 0; j < 8; ++j) {
    const int i = base + j;
    v[j] = (i < n) ? deg[i] : 0;
    s += v[j];
  }
  int ws = s;
  for (int off = 1; off < 64; off <<= 1) {
    const int t = __shfl_up(ws, off);
    if (lane >= off) ws += t;
  }
  if (lane == 63) wsum[wid] = ws;
  __syncthreads();
  int woff = 0;
  for (int w_ = 0; w_ < wid; ++w_) woff += wsum[w_];
  int run = blockoff + woff + (ws - s);
#pragma unroll
  for (int j = 0; j < 8; ++j) {
    const int i = base + j;
    if (i < n) {
      cursor[i] = run;
      row_ptr[i + 1] = run + v[j];
    }
    run += v[j];
  }
  if (blockIdx.x == 0 && tid == 0) row_ptr[0] = 0;
}

// CSR entry interleaved: .x = src node, .y = exp-weight bits (one 8B txn per edge)
__global__ void edge_scatter(const int* __restrict__ src, const int* __restrict__ dst,
                             const float* __restrict__ eexp, int* __restrict__ cursor,
                             int2* __restrict__ csr, int E, int n) {
  const int e = blockIdx.x * 256 + threadIdx.x;
  if (e >= E) return;
  const int s = src[e], d = dst[e];
  if ((unsigned)s >= (unsigned)n || (unsigned)d >= (unsigned)n) return;
  const int pos = atomicAdd(&cursor[d], 1);
  int2 c;
  c.x = s;
  c.y = __float_as_int(eexp[e]);
  csr[pos] = c;
}

// out[d,:] = elu( (sum_e ex_e * hpre[src_e,:]) / (sum ex + eps) ), 256-dim rows.
// Edge list preloaded into lane regs (1 coalesced 8B load/lane, deg<=64), shfl-
// distributed; predicated unified 16-edge/iter loop (no csr latency chain, no
// serialized tail). half-wave (32 lanes x 16B = 512B row) per edge slot.
__global__ __launch_bounds__(256) void gat_prop256(const unsigned short* __restrict__ hpre,
                                                   const int* __restrict__ row_ptr,
                                                   const int2* __restrict__ csr,
                                                   unsigned short* __restrict__ out, int n) {
  const int node = blockIdx.x * 4 + (threadIdx.x >> 6);
  if (node >= n) return;
  const int lane = threadIdx.x & 63;
  const int half = lane >> 5;
  const int lh = lane & 31;
  const int beg = row_ptr[node], end = row_ptr[node + 1];
  const int deg = end - beg;
  const unsigned short* base = hpre + (lh << 3);
  float a[8] = {0.f, 0.f, 0.f, 0.f, 0.f, 0.f, 0.f, 0.f};
  float wsum = 0.f;

  int cs = 0;
  float cw = 0.f;
  if (lane < deg) {
    const int2 t = csr[beg + lane];
    cs = t.x;
    cw = __int_as_float(t.y);
  }
  const int dmain = deg < 64 ? deg : 64;
  for (int j0 = 0; j0 < dmain; j0 += 16) {
#pragma unroll
    for (int u = 0; u < 8; ++u) {
      const int j = j0 + 2 * u + half;
      const bool valid = j < dmain;
      const int jj = valid ? j : 0;
      const int s = __shfl(cs, jj);
      float w = __shfl(cw, jj);
      w = valid ? w : 0.f;
      const u32x4 v = *(const u32x4*)(base + (size_t)s * HID);
      wsum += w;
      a[0] += w * bf2f((unsigned short)(v.x & 0xffffu));
      a[1] += w * bf2f((unsigned short)(v.x >> 16));
      a[2] += w * bf2f((unsigned short)(v.y & 0xffffu));
      a[3] += w * bf2f((unsigned short)(v.y >> 16));
      a[4] += w * bf2f((unsigned short)(v.z & 0xffffu));
      a[5] += w * bf2f((unsigned short)(v.z >> 16));
      a[6] += w * bf2f((unsigned short)(v.w & 0xffffu));
      a[7] += w * bf2f((unsigned short)(v.w >> 16));
    }
  }
  // rare tail: deg > 64
  for (int e = beg + 64; e < end; e += 2) {
    const int e2 = e + half;
    if (e2 < end) {
      const int2 c = csr[e2];
      const float w = __int_as_float(c.y);
      const u32x4 v = *(const u32x4*)(base + (size_t)c.x * HID);
      wsum += w;
      a[0] += w * bf2f((unsigned short)(v.x & 0xffffu));
      a[1] += w * bf2f((unsigned short)(v.x >> 16));
      a[2] += w * bf2f((unsigned short)(v.y & 0xffffu));
      a[3] += w * bf2f((unsigned short)(v.y >> 16));
      a[4] += w * bf2f((unsigned short)(v.z & 0xffffu));
      a[5] += w * bf2f((unsigned short)(v.z >> 16));
      a[6] += w * bf2f((unsigned short)(v.w & 0xffffu));
      a[7] += w * bf2f((unsigned short)(v.w >> 16));
    }
  }
#pragma unroll
  for (int i = 0; i < 8; ++i) a[i] += __shfl_xor(a[i], 32);
  wsum += __shfl_xor(wsum, 32);
  if (half == 0) {
    const float inv = 1.f / (wsum + 1e-16f);
#pragma unroll
    for (int i = 0; i < 8; ++i) {
      a[i] *= inv;
      a[i] = a[i] > 0.f ? a[i] : (expf(a[i]) - 1.f);
    }
    u32x4 o;
    o.x = (unsigned int)f2bf(a[0]) | ((unsigned int)f2bf(a[1]) << 16);
    o.y = (unsigned int)f2bf(a[2]) | ((unsigned int)f2bf(a[3]) << 16);
    o.z = (unsigned int)f2bf(a[4]) | ((unsigned int)f2bf(a[5]) << 16);
    o.w = (unsigned int)f2bf(a[6]) | ((unsigned int)f2bf(a[7]) << 16);
    *(u32x4*)(out + (size_t)node * HID + (lh << 3)) = o;
  }
}

// g2[d,:] = (sum_e ex_e * h2[src_e,:]) / (sum ex + eps), 64-dim rows, NO elu (fused
// into the following gemm via linearity). Same preload+predication; quarter-wave
// (16 lanes x 8B = 128B row) per edge slot; 16 edges/iter.
__global__ __launch_bounds__(256) void gat_prop64(const unsigned short* __restrict__ hpre,
                                                  const int* __restrict__ row_ptr,
                                                  const int2* __restrict__ csr,
                                                  unsigned short* __restrict__ out, int n) {
  const int node = blockIdx.x * 4 + (threadIdx.x >> 6);
  if (node >= n) return;
  const int lane = threadIdx.x & 63;
  const int quad = lane >> 4;
  const int lr = lane & 15;
  const int beg = row_ptr[node], end = row_ptr[node + 1];
  const int deg = end - beg;
  const unsigned short* base = hpre + (lr << 2);
  float a0 = 0.f, a1 = 0.f, a2 = 0.f, a3 = 0.f, wsum = 0.f;

  int cs = 0;
  float cw = 0.f;
  if (lane < deg) {
    const int2 t = csr[beg + lane];
    cs = t.x;
    cw = __int_as_float(t.y);
  }
  const int dmain = deg < 64 ? deg : 64;
  for (int j0 = 0; j0 < dmain; j0 += 16) {
#pragma unroll
    for (int u = 0; u < 4; ++u) {
      const int j = j0 + 4 * u + quad;
      const bool valid = j < dmain;
      const int jj = valid ? j : 0;
      const int s = __shfl(cs, jj);
      float w = __shfl(cw, jj);
      w = valid ? w : 0.f;
      const uint2 v = *(const uint2*)(base + (size_t)s * OUTD);
      wsum += w;
      a0 += w * bf2f((unsigned short)(v.x & 0xffffu));
      a1 += w * bf2f((unsigned short)(v.x >> 16));
      a2 += w * bf2f((unsigned short)(v.y & 0xffffu));
      a3 += w * bf2f((unsigned short)(v.y >> 16));
    }
  }
  for (int e = beg + 64; e < end; e += 4) {
    const int e2 = e + quad;
    if (e2 < end) {
      const int2 c = csr[e2];
      const float w = __int_as_float(c.y);
      const uint2 v = *(const uint2*)(base + (size_t)c.x * OUTD);
      wsum += w;
      a0 += w * bf2f((unsigned short)(v.x & 0xffffu));
      a1 += w * bf2f((unsigned short)(v.x >> 16));
      a2 += w * bf2f((unsigned short)(v.y & 0xffffu));
      a3 += w * bf2f((unsigned short)(v.y >> 16));
    }
  }
  a0 += __shfl_xor(a0, 16); a0 += __shfl_xor(a0, 32);
  a1 += __shfl_xor(a1, 16); a1 += __shfl_xor(a1, 32);
  a2 += __shfl_xor(a2, 16); a2 += __shfl_xor(a2, 32);
  a3 += __shfl_xor(a3, 16); a3 += __shfl_xor(a3, 32);
  wsum += __shfl_xor(wsum, 16); wsum += __shfl_xor(wsum, 32);
  if (quad == 0) {
    const float inv = 1.f / (wsum + 1e-16f);
    uint2 o;
    o.x = (unsigned int)f2bf(a0 * inv) | ((unsigned int)f2bf(a1 * inv) << 16);
    o.y = (unsigned int)f2bf(a2 * inv) | ((unsigned int)f2bf(a3 * inv) << 16);
    *(uint2*)(out + (size_t)node * OUTD + (lr << 2)) = o;
  }
}

extern "C" void kernel_launch(void* const* d_in, const int* in_sizes, int n_in,
                              void* d_out, int out_size, void* d_ws, size_t ws_size,
                              hipStream_t stream) {
  const float* feat = (const float*)d_in[0];   // [N, 512] fp32
  const float* W1 = (const float*)d_in[1];     // [512, 256] fp32
  const float* W2 = (const float*)d_in[2];     // [256, 64] fp32
  const float* att_s = (const float*)d_in[3];  // [256] fp32
  const float* att_d = (const float*)d_in[4];  // [256] fp32
  const int* ei = (const int*)d_in[5];         // [2, E] int32
  const int N = in_sizes[0] / IN_DIM;          // 50000
  const int E = in_sizes[5] / 2;               // 600000
  const int* src = ei;
  const int* dst = ei + E;
  float* outf = (float*)d_out;  // h2 [N,64] fp32 ++ h4 [N,512] fp32

  // Park hp1/g2 in the not-yet-written h4 slot. Lifetimes strictly sequential:
  // hp1 dead after gat_prop256; g2 dead after the conv3' gemm; conv4 writes the
  // slot last reading only ws.
  unsigned short* hp1 = (unsigned short*)(outf + (size_t)N * OUTD);  // [N,256] bf16
  unsigned short* g2 = hp1 + (size_t)N * HID;                        // [N,64] bf16

  // ---- workspace carve-up (256B-aligned) ----
  char* w = (char*)d_ws;
  size_t off = 0;
  auto alloc = [&](size_t bytes) -> void* {
    void* p = w + off;
    off += (bytes + 255) & ~(size_t)255;
    return p;
  };
  unsigned short* h1h3 = (unsigned short*)alloc((size_t)N * HID * 2);  // h1, then h3
  unsigned short* h2b = (unsigned short*)alloc((size_t)N * OUTD * 2);  // h2 bf16
  float* a_src_v = (float*)alloc((size_t)N * 4);
  float* a_dst_v = (float*)alloc((size_t)N * 4);
  float* eexp = (float*)alloc((size_t)E * 4);
  int* deg = (int*)alloc((size_t)N * 4);
  int* row_ptr = (int*)alloc((size_t)(N + 1) * 4);
  int* cursor = (int*)alloc((size_t)N * 4);
  int* bsum = (int*)alloc((size_t)64 * 4);
  int2* csr = (int2*)alloc((size_t)E * 8);
  unsigned short* W1T = (unsigned short*)alloc((size_t)IN_DIM * HID * 2);  // [256,512] bf16
  unsigned short* W1b = (unsigned short*)alloc((size_t)IN_DIM * HID * 2);  // [512,256] bf16
  unsigned short* W2T = (unsigned short*)alloc((size_t)HID * OUTD * 2);    // [64,256] bf16
  unsigned short* W2b = (unsigned short*)alloc((size_t)HID * OUTD * 2);    // [256,64] bf16

  const int EB = (E + 255) / 256;
  const int NB = (N + 255) / 256;
  const int MB = (N + 127) / 128;
  const int SB = (N + 2047) / 2048;  // scan blocks (25 for N=50000; must be <= 64)

  // weight conversions (one launch)
  cvt_weights<<<(IN_DIM * HID + 255) / 256, 256, 0, stream>>>(W1, W2, W1T, W1b, W2T, W2b);

  // conv1: hp1 = feat @ W1 (fp32 A converted in staging)
  gemm_a32_bt<128, 128><<<dim3(MB, HID / 128), 256, 0, stream>>>(feat, W1T, hp1,
                                                                 N, HID, IN_DIM);
  rowdot<<<(N + 3) / 4, 256, 0, stream>>>(hp1, att_s, att_d, a_src_v, a_dst_v, N);

  // edge softmax (tied: shared by conv1 & conv3) + dst-CSR build (no denom atomics)
  init_deg<<<NB, 256, 0, stream>>>(deg, N);
  edge_pass1<<<EB, 256, 0, stream>>>(src, dst, a_src_v, a_dst_v, eexp, deg, E, N);
  scan_reduce<<<SB, 256, 0, stream>>>(deg, bsum, N);
  scan_final<<<SB, 256, 0, stream>>>(deg, bsum, row_ptr, cursor, N);
  edge_scatter<<<EB, 256, 0, stream>>>(src, dst, eexp, cursor, csr, E, N);

  // conv1 propagate (self-normalizing) + elu -> h1 (bf16)
  gat_prop256<<<(N + 3) / 4, 256, 0, stream>>>(hp1, row_ptr, csr, h1h3, N);
  // conv2: h2 = h1 @ W2 -> outf (fp32) + h2b (bf16)
  gemm_bt<128, 64><<<dim3(MB, OUTD / 64), 256, 0, stream>>>(h1h3, W2T, outf, h2b,
                                                            N, OUTD, HID, 1, 0);
  // conv3 via linearity: g2 = prop(h2) [N,64], then h3 = elu(g2 @ W2^T)
  gat_prop64<<<(N + 3) / 4, 256, 0, stream>>>(h2b, row_ptr, csr, g2, N);
  gemm_bt<128, 128><<<dim3(MB, HID / 128), 256, 0, stream>>>(g2, W2b, h1h3, nullptr,
                                                             N, HID, OUTD, 0, 1);
  // conv4: h4 = h3 @ W1^T -> outf[N*64:] (fp32)
  gemm_bt<128, 128><<<dim3(MB, IN_DIM / 128), 256, 0, stream>>>(h1h3, W1b,
                                                                outf + (size_t)N * OUTD,
                                                                nullptr, N, IN_DIM, HID, 1, 0);
}